// Round 12
// baseline (39.794 us; speedup 1.0000x reference)
//
#include <hip/hip_runtime.h>

// PolyAttn collapse: a = s^4/|s^4| == 1.0 identically, so
//   out[b,n,:] = vsum[b,:] @ w_o  (independent of n, q, k, alpha),
//   vsum[b,:]  = (sum_n x[b,n,:]) @ w_qkv[:, 2H:3H].
// R12: kill ALL low-concurrency nodes and the orow round-trip.
//   kZ (4 blk): zero vsum.
//   kXV (256 blk): colsum 16-slice of x, @Wv slice, atomicAdd -> vsum
//       (atomic contention proven free in R8; kills vspart+kFold).
//   kOB (512 blk): orow 32-col slice from vsum@Wo, broadcast to 512 rows
//       as full 128B line chunks (kills the orow node + partial lines).
// Grid barriers ~15us / spin-waits ~100us on 8-XCD (R3/R4/R7) -> banned.

#define B_ 4
#define N_ 2048
#define D_ 1024
#define H_ 1024
#define H3_ 3072

__device__ __forceinline__ void f4add(float4& a, const float4 b) {
    a.x += b.x; a.y += b.y; a.z += b.z; a.w += b.w;
}

// ws layout (floats): vsum[4][1024]

// ---- kZ: zero vsum (1024 float4s) ------------------------------------------
__global__ __launch_bounds__(256) void kZ(float4* __restrict__ vsum4) {
    vsum4[blockIdx.x * 256 + threadIdx.x] = make_float4(0.f, 0.f, 0.f, 0.f);
}

// ---- kXV: 256 blocks (b*64+s): colsum x[b,:,s*16..+16], @Wv slice, atomic --
__global__ __launch_bounds__(256) void kXV(const float* __restrict__ x,
                                           const float* __restrict__ w_qkv,
                                           float* __restrict__ vsum) {
    const int blk = blockIdx.x;
    const int b = blk >> 6, s = blk & 63;
    const int t = threadIdx.x;
    const int c4 = t & 3;                  // float4 col within 16-float slice
    const int rs = t >> 2;                 // 64 row streams
    __shared__ float4 s_acc[256];

    const float4* x4 = reinterpret_cast<const float4*>(x);
    float4 acc = make_float4(0.f, 0.f, 0.f, 0.f);
    size_t base = ((size_t)b * N_ + rs) * (D_ / 4) + s * 4 + c4;
#pragma unroll 16
    for (int i = 0; i < 32; ++i)           // rows rs + 64*i
        f4add(acc, x4[base + (size_t)i * 64 * (D_ / 4)]);
    s_acc[t] = acc;
    __syncthreads();
    for (int off = 128; off >= 4; off >>= 1) {
        if (t < off) f4add(s_acc[t], s_acc[t + off]);
        __syncthreads();
    }
    // s_acc[0..3] = cs[16] = colsum of the 16-float slice
    const float* cs = reinterpret_cast<const float*>(s_acc);
    const float4* wv4 = reinterpret_cast<const float4*>(w_qkv);
    float4 vp = make_float4(0.f, 0.f, 0.f, 0.f);
    size_t wbase = (size_t)(s * 16) * (H3_ / 4) + (2 * H_ / 4) + t;
#pragma unroll
    for (int j = 0; j < 16; ++j) {
        const float c = cs[j];
        const float4 w = wv4[wbase + (size_t)j * (H3_ / 4)];  // 4KB coalesced
        vp.x += c * w.x; vp.y += c * w.y; vp.z += c * w.z; vp.w += c * w.w;
    }
    float* dst = vsum + b * H_ + t * 4;
    atomicAdd(dst + 0, vp.x);
    atomicAdd(dst + 1, vp.y);
    atomicAdd(dst + 2, vp.z);
    atomicAdd(dst + 3, vp.w);
}

// ---- kOB: 512 blocks (b, sl in 0..31, rq in 0..3) ---------------------------
// orow slice (32 cols) = sum_h vsum[b,h]*Wo[h, sl*32..+32]; write rows
// rq*512..+512 as 128B chunks.
__global__ __launch_bounds__(256) void kOB(const float* __restrict__ vsum,
                                           const float* __restrict__ w_o,
                                           float* __restrict__ out) {
    const int blk = blockIdx.x;
    const int b  = blk >> 7;
    const int sl = (blk >> 2) & 31;
    const int rq = blk & 3;
    const int t  = threadIdx.x;
    __shared__ float s_vs[D_];             // vsum[b,:]
    __shared__ float s_par[8][33];         // [hg][c] padded
    __shared__ float s_or[32];             // the 32-col orow slice

    // load vsum[b]
    reinterpret_cast<float4*>(s_vs)[t] = ((const float4*)vsum)[b * 256 + t];
    __syncthreads();
    // partial[hg][c]: hg = t>>5 (8 groups x 128 h), c = t&31
    {
        const int c = t & 31, hg = t >> 5;
        float a = 0.f;
        const float* wo = w_o + (size_t)(hg * 128) * D_ + sl * 32 + c;
#pragma unroll 8
        for (int j = 0; j < 128; ++j)
            a += s_vs[hg * 128 + j] * wo[(size_t)j * D_];
        s_par[hg][c] = a;
    }
    __syncthreads();
    if (t < 32) {
        float a = 0.f;
#pragma unroll
        for (int g = 0; g < 8; ++g) a += s_par[g][t];
        s_or[t] = a;
    }
    __syncthreads();
    // broadcast: 512 rows x 32 floats (8 float4 = 128B per row)
    const float4 val = reinterpret_cast<const float4*>(s_or)[t & 7];
    float4* out4 = reinterpret_cast<float4*>(out);
    const int r0 = rq * 512 + (t >> 3);    // 32 row streams
    size_t base = ((size_t)b * N_ + r0) * (D_ / 4) + sl * 8 + (t & 7);
#pragma unroll 16
    for (int i = 0; i < 16; ++i)           // rows r0 + 32*i
        out4[base + (size_t)i * 32 * (D_ / 4)] = val;
}

extern "C" void kernel_launch(void* const* d_in, const int* in_sizes, int n_in,
                              void* d_out, int out_size, void* d_ws, size_t ws_size,
                              hipStream_t stream) {
    const float* x     = (const float*)d_in[0];   // [B, N, D]
    const float* w_qkv = (const float*)d_in[1];   // [D, 3H]
    const float* w_o   = (const float*)d_in[2];   // [H, D]
    // d_in[3] = alpha — provably unused (a == 1 regardless of alpha).
    float* out = (float*)d_out;                   // [B, N, D] fp32

    float* vsum = (float*)d_ws;                   // 4096 floats

    kZ<<<4, 256, 0, stream>>>((float4*)vsum);
    kXV<<<256, 256, 0, stream>>>(x, w_qkv, vsum);
    kOB<<<512, 256, 0, stream>>>(vsum, w_o, out);
}

// Round 13
// 29.770 us; speedup vs baseline: 1.3367x; 1.3367x over previous
//
#include <hip/hip_runtime.h>

// PolyAttn collapse: a = s^4/|s^4| == 1.0 identically, so
//   out[b,n,:] = vsum[b,:] @ w_o  (independent of n, q, k, alpha),
//   vsum[b,:]  = (sum_n x[b,n,:]) @ w_qkv[:, 2H:3H].
// R13: cost-model refit (R7 anchor: inter-node ovh ~0, dur = sum of kernel
// times) says the ~15us sink in every prior pipeline is the LOW-CONCURRENCY
// reduce stage (4-64 blocks doing cross-XCD partial gathers). So: 2 nodes,
// both 256 blocks, no narrow stage. kOut2 folds vspart redundantly per
// block (wide streaming L2 reads) instead of a narrow kFold/kB.
// Grid barriers ~15us / spin-waits ~100us (R3/R4/R7) -> banned.
// Deep strided j-loops (R12 kOB, 1024-deep) -> latency-bound, banned.

#define B_ 4
#define N_ 2048
#define D_ 1024
#define H_ 1024
#define H3_ 3072

__device__ __forceinline__ void f4add(float4& a, const float4 b) {
    a.x += b.x; a.y += b.y; a.z += b.z; a.w += b.w;
}

// ws layout (floats): vspart[64][4][1024] (1 MB)

// ---- kXV: 256 blocks (b*64+s): colsum x[b,:,s*16..+16] then @Wv slice ------
__global__ __launch_bounds__(256) void kXV(const float* __restrict__ x,
                                           const float* __restrict__ w_qkv,
                                           float4* __restrict__ vspart4) {
    const int blk = blockIdx.x;
    const int b = blk >> 6, s = blk & 63;
    const int t = threadIdx.x;
    const int c4 = t & 3;                  // float4 col within 16-float slice
    const int rs = t >> 2;                 // 64 row streams
    __shared__ float4 s_acc[256];

    const float4* x4 = reinterpret_cast<const float4*>(x);
    float4 acc = make_float4(0.f, 0.f, 0.f, 0.f);
    size_t base = ((size_t)b * N_ + rs) * (D_ / 4) + s * 4 + c4;
#pragma unroll 16
    for (int i = 0; i < 32; ++i)           // rows rs + 64*i
        f4add(acc, x4[base + (size_t)i * 64 * (D_ / 4)]);
    s_acc[t] = acc;
    __syncthreads();
    for (int off = 128; off >= 4; off >>= 1) {
        if (t < off) f4add(s_acc[t], s_acc[t + off]);
        __syncthreads();
    }
    // s_acc[0..3] = cs[16] = colsum of the 16-float slice of x[b]
    const float* cs = reinterpret_cast<const float*>(s_acc);
    const float4* wv4 = reinterpret_cast<const float4*>(w_qkv);
    float4 vp = make_float4(0.f, 0.f, 0.f, 0.f);
    size_t wbase = (size_t)(s * 16) * (H3_ / 4) + (2 * H_ / 4) + t;
#pragma unroll
    for (int j = 0; j < 16; ++j) {         // 16 contiguous Wv rows, 1KB each
        const float c = cs[j];
        const float4 w = wv4[wbase + (size_t)j * (H3_ / 4)];
        vp.x += c * w.x; vp.y += c * w.y; vp.z += c * w.z; vp.w += c * w.w;
    }
    vspart4[(size_t)(s * 4 + b) * 256 + t] = vp;   // plain store
}

// ---- kOut2: 256 blocks (b, sl in 0..31, rh in 0..1) ------------------------
// fold vspart -> vsum[b] (in LDS), orow 32-col slice = vsum[b]@Wo[:,slice],
// broadcast to 1024 rows as 128B chunks. All wide, all streaming.
__global__ __launch_bounds__(256) void kOut2(const float4* __restrict__ vspart4,
                                             const float* __restrict__ w_o,
                                             float* __restrict__ out) {
    const int blk = blockIdx.x;
    const int b  = blk >> 6;
    const int sl = (blk >> 1) & 31;
    const int rh = blk & 1;
    const int t  = threadIdx.x;
    __shared__ float4 s_vs4[256];          // vsum[b,:] as 256 float4
    __shared__ float4 s_par[32][8];        // [hg][c] partials, 4KB
    __shared__ float4 s_or4[8];            // 32-col orow slice

    // fold: vsum[b][4t..4t+3] = sum_s vspart[s][b][...]  (wave streams 1KB/instr)
    {
        const float4* p = vspart4 + b * 256 + t;
        float4 acc = make_float4(0.f, 0.f, 0.f, 0.f);
#pragma unroll 16
        for (int s = 0; s < 64; ++s)
            f4add(acc, p[(size_t)s * 1024]);
        s_vs4[t] = acc;
    }
    __syncthreads();
    // matmul: c = t&7 (float4 col in 32-float slice), hg = t>>3 (32 h-groups)
    {
        const int c = t & 7, hg = t >> 3;
        const float* vs = reinterpret_cast<const float*>(s_vs4);
        const float4* wo4 = reinterpret_cast<const float4*>(w_o);
        float4 acc = make_float4(0.f, 0.f, 0.f, 0.f);
        size_t wbase = (size_t)(hg * 32) * (D_ / 4) + sl * 8 + c;
#pragma unroll 8
        for (int j = 0; j < 32; ++j) {     // 32 rows per group, 128B chunks
            const float v = vs[hg * 32 + j];
            const float4 w = wo4[wbase + (size_t)j * (D_ / 4)];
            acc.x += v * w.x; acc.y += v * w.y; acc.z += v * w.z; acc.w += v * w.w;
        }
        s_par[hg][c] = acc;
    }
    __syncthreads();
    if (t < 8) {                           // fold 32 h-groups per col
        float4 a = s_par[0][t];
#pragma unroll
        for (int g = 1; g < 32; ++g) f4add(a, s_par[g][t]);
        s_or4[t] = a;
    }
    __syncthreads();
    // broadcast: 1024 rows (rh half) x 32 cols; per instr 8 rows x 128B
    const float4 val = s_or4[t & 7];
    float4* out4 = reinterpret_cast<float4*>(out);
    const int r0 = rh * 1024 + (t >> 3);   // 32 row streams
    size_t base = ((size_t)b * N_ + r0) * (D_ / 4) + sl * 8 + (t & 7);
#pragma unroll 16
    for (int i = 0; i < 32; ++i)           // rows r0 + 32*i
        out4[base + (size_t)i * 32 * (D_ / 4)] = val;
}

extern "C" void kernel_launch(void* const* d_in, const int* in_sizes, int n_in,
                              void* d_out, int out_size, void* d_ws, size_t ws_size,
                              hipStream_t stream) {
    const float* x     = (const float*)d_in[0];   // [B, N, D]
    const float* w_qkv = (const float*)d_in[1];   // [D, 3H]
    const float* w_o   = (const float*)d_in[2];   // [H, D]
    // d_in[3] = alpha — provably unused (a == 1 regardless of alpha).
    float* out = (float*)d_out;                   // [B, N, D] fp32

    float* vspart = (float*)d_ws;                 // 64*4*1024 = 262144 floats

    kXV<<<256, 256, 0, stream>>>(x, w_qkv, (float4*)vspart);
    kOut2<<<256, 256, 0, stream>>>((const float4*)vspart, w_o, out);
}